// Round 7
// baseline (24.263 us; speedup 1.0000x reference)
//
#include <hip/hip_runtime.h>

#define LENY  1048576
#define NU    (LENY - 1)      // length of u_combined
#define NRBF  11
#define NB    2048            // 8 blocks/CU -> 32 waves/CU (exact-fit co-resident)
#define NT    256             // 4 waves per block
#define NW    (NT / 64)
#define PERT  2               // consecutive elements per thread
#define CHUNK (NT * PERT)     // 512; NB*CHUNK == LENY

typedef float v4f __attribute__((ext_vector_type(4)));

#define L2E 1.44269504088896340736f   // log2(e)

__device__ __forceinline__ float fexp(float x) {
    return __builtin_amdgcn_exp2f(x * L2E);
}
__device__ __forceinline__ float sigmoid10(float x) {
    x = fminf(10.0f, fmaxf(-10.0f, x));
    const float e = __builtin_amdgcn_exp2f(-x * L2E);
    return __builtin_amdgcn_rcpf(1.0f + e);
}

// Relaxed agent-scope atomics: reach the coherence point, emit NO
// buffer_inv/buffer_wbl2 (acq/rel cache maintenance poisoned R2: 62us).
__device__ __forceinline__ void st_relaxed_u64(unsigned long long* p, unsigned long long v) {
    __hip_atomic_store(p, v, __ATOMIC_RELAXED, __HIP_MEMORY_SCOPE_AGENT);
}
__device__ __forceinline__ unsigned long long ld_relaxed_u64(const unsigned long long* p) {
    return __hip_atomic_load(p, __ATOMIC_RELAXED, __HIP_MEMORY_SCOPE_AGENT);
}
__device__ __forceinline__ void st_relaxed_u32(unsigned* p, unsigned v) {
    __hip_atomic_store(p, v, __ATOMIC_RELAXED, __HIP_MEMORY_SCOPE_AGENT);
}
__device__ __forceinline__ unsigned ld_relaxed_u32(const unsigned* p) {
    return __hip_atomic_load(p, __ATOMIC_RELAXED, __HIP_MEMORY_SCOPE_AGENT);
}

__global__ __launch_bounds__(NT, 8) void rbf_fused(
    const float2* __restrict__ yin,
    const float2* __restrict__ xa,
    const float2* __restrict__ xb,
    const float*  __restrict__ rbfw_raw,
    const float*  __restrict__ weights,
    const float*  __restrict__ g1raw,
    const float*  __restrict__ g2raw,
    float2* __restrict__ yout,
    float2* __restrict__ uout,
    double2* __restrict__ bsums,
    unsigned* __restrict__ flags)
{
    const int b = blockIdx.x, t = threadIdx.x;
    const int lane = t & 63, wid = t >> 6;
    const int base = b * CHUNK + t * PERT;

    // ---- uniform params ----
    const float RBFw    = sigmoid10(rbfw_raw[0]);
    const float wdt     = RBFw * 0.2f;
    const float negInvL = -L2E / (2.0f * wdt * wdt);
    const float g1 = fexp(g1raw[0]);
    const float g2 = fexp(g2raw[0]);
    const float Bf = (float)(1.0 / 60.0);
    const float2 y0 = yin[0];

    float wj[NRBF];
    #pragma unroll
    for (int j = 0; j < NRBF; ++j) wj[j] = weights[j];

    // ---- 16B/lane nontemporal input loads ----
    const v4f yv = __builtin_nontemporal_load((const v4f*)yin + (base >> 1));
    const v4f av = __builtin_nontemporal_load((const v4f*)xa  + (base >> 1));
    const v4f bv = __builtin_nontemporal_load((const v4f*)xb  + (base >> 1));

    // ---- compute u in registers, per-thread double sums ----
    float ux[PERT], uy[PERT];
    double sx = 0.0, sy = 0.0;
    #pragma unroll
    for (int k = 0; k < PERT; ++k) {
        const int gi = base + k;
        const float ti = ((float)gi - 524287.5f) / 524287.5f;
        float dot = 0.0f;
        #pragma unroll
        for (int j = 0; j < NRBF; ++j) {
            const float c = -1.0f + 0.2f * (float)j;
            const float d = ti - c;
            dot += __builtin_amdgcn_exp2f(d * d * negInvL) * wj[j];
        }
        const float wt = sigmoid10(dot);
        const float eyx = yv[2*k], eyy = yv[2*k+1];
        const float eax = av[2*k], eay = av[2*k+1];
        const float ebx = bv[2*k], eby = bv[2*k+1];
        const float u1x = -g1 * (eyx - eax);
        const float u1y = -g1 * (eyy - eay);
        const float u2x = -g2 * (eyx - ebx);
        const float u2y = -g2 * (eyy - eby);
        ux[k] = u1x * (1.0f - wt) + u2x * wt;
        uy[k] = u1y * (1.0f - wt) + u2y * wt;
        sx += (double)(ux[k] * Bf);   // phantom elem LENY-1: exclusive scan means
        sy += (double)(uy[k] * Bf);   // it never reaches any stored prefix
    }

    // ---- block scan: wave shfl_up + wave totals (1 barrier) ----
    double ix = sx, iy = sy;
    #pragma unroll
    for (int d = 1; d < 64; d <<= 1) {
        const double px = __shfl_up(ix, d, 64);
        const double py = __shfl_up(iy, d, 64);
        if (lane >= d) { ix += px; iy += py; }
    }
    __shared__ double2 wtot[NW];
    if (lane == 63) wtot[wid] = make_double2(ix, iy);
    __syncthreads();
    double wbx = 0.0, wby = 0.0, totx = 0.0, toty = 0.0;
    #pragma unroll
    for (int w = 0; w < NW; ++w) {
        const double vx = wtot[w].x, vy = wtot[w].y;
        totx += vx; toty += vy;
        if (w < wid) { wbx += vx; wby += vy; }
    }
    const double myex = wbx + ix - sx;   // exclusive in-block prefix
    const double myey = wby + iy - sy;

    // ---- publish ASAP: payload -> vmcnt(0) -> flag ----
    if (t == 0) {
        st_relaxed_u64((unsigned long long*)&bsums[b].x, __builtin_bit_cast(unsigned long long, totx));
        st_relaxed_u64((unsigned long long*)&bsums[b].y, __builtin_bit_cast(unsigned long long, toty));
        asm volatile("s_waitcnt vmcnt(0)" ::: "memory");
        st_relaxed_u32(&flags[b], 1u);
    }

    // ---- store u AFTER publish (overlaps the lookback wait) ----
    if (base + PERT <= NU) {
        v4f r = { ux[0], uy[0], ux[1], uy[1] };
        __builtin_nontemporal_store(r, (v4f*)uout + (base >> 1));
    } else {
        for (int k = 0; k < PERT; ++k)
            if (base + k < NU) uout[base + k] = make_float2(ux[k], uy[k]);
    }

    // ---- lookback: <=8 predecessors per thread, relaxed spin ----
    double ox = 0.0, oy = 0.0;
    for (int j = t; j < b; j += NT) {
        while (ld_relaxed_u32(&flags[j]) == 0u) __builtin_amdgcn_s_sleep(1);
        asm volatile("" ::: "memory");
        ox += __builtin_bit_cast(double, ld_relaxed_u64((const unsigned long long*)&bsums[j].x));
        oy += __builtin_bit_cast(double, ld_relaxed_u64((const unsigned long long*)&bsums[j].y));
    }

    // ---- reduce offset partials: wave shfl + wave totals ----
    #pragma unroll
    for (int d = 32; d > 0; d >>= 1) {
        ox += __shfl_down(ox, d);
        oy += __shfl_down(oy, d);
    }
    __shared__ double2 wred[NW];
    if (lane == 0) wred[wid] = make_double2(ox, oy);
    __syncthreads();
    double offx = 0.0, offy = 0.0;
    #pragma unroll
    for (int w = 0; w < NW; ++w) { offx += wred[w].x; offy += wred[w].y; }

    // ---- exclusive-scan y write (16B nt stores; y[0]=yin[0] falls out) ----
    double runx = offx + myex, runy = offy + myey;
    const double y0x = (double)y0.x, y0y = (double)y0.y;

    const float o0x = (float)(y0x + runx);
    const float o0y = (float)(y0y + runy);
    runx += (double)(ux[0] * Bf);
    runy += (double)(uy[0] * Bf);
    const float o1x = (float)(y0x + runx);
    const float o1y = (float)(y0y + runy);
    v4f r = { o0x, o0y, o1x, o1y };
    __builtin_nontemporal_store(r, (v4f*)yout + (base >> 1));
}

extern "C" void kernel_launch(void* const* d_in, const int* in_sizes, int n_in,
                              void* d_out, int out_size, void* d_ws, size_t ws_size,
                              hipStream_t stream) {
    const float2* yin  = (const float2*)d_in[0];
    const float2* xa   = (const float2*)d_in[1];
    const float2* xb   = (const float2*)d_in[2];
    const float*  rbfw = (const float*)d_in[3];
    const float*  wts  = (const float*)d_in[4];
    const float*  g1   = (const float*)d_in[5];
    const float*  g2   = (const float*)d_in[6];

    float*  out  = (float*)d_out;
    float2* yout = (float2*)out;                 // y: LENY x 2
    float2* uout = (float2*)(out + 2 * LENY);    // u_combined: (LENY-1) x 2

    double2*  bsums = (double2*)d_ws;                                  // 32 KB
    unsigned* flags = (unsigned*)((char*)d_ws + NB * sizeof(double2)); //  8 KB

    // flags must be 0 at kernel start on every replay (d_ws not re-poisoned).
    hipMemsetAsync(flags, 0, NB * sizeof(unsigned), stream);

    rbf_fused<<<NB, NT, 0, stream>>>(yin, xa, xb, rbfw, wts, g1, g2,
                                     yout, uout, bsums, flags);
}